// Round 5
// baseline (2447.452 us; speedup 1.0000x reference)
//
#include <hip/hip_runtime.h>

#define Bsz 512
#define Ssz 512
#define Isz 32
#define Hsz 128
#define BB  1            // one batch row per block -> grid 512 -> 2 blocks/CU
#define NT  512          // 8 waves
#define SI  (Ssz*Isz)    // 16384
#define HROW 144         // shorts per h row: 288 B stride
#define LOG2E 1.44269504088896340736f

typedef __attribute__((ext_vector_type(8))) short bf16x8;
typedef __attribute__((ext_vector_type(4))) float f32x4;

__device__ __forceinline__ unsigned cvtpk(float lo, float hi){
  unsigned r; asm("v_cvt_pk_bf16_f32 %0, %1, %2" : "=v"(r) : "v"(lo), "v"(hi));
  return r;
}
__device__ __forceinline__ unsigned short f2bf(float f){      // RNE f32->bf16
  unsigned u = __float_as_uint(f);
  return (unsigned short)((u + 0x7FFFu + ((u >> 16) & 1u)) >> 16);
}
__device__ __forceinline__ float sigm_p(float xp){            // pre-scaled by log2e
  return __builtin_amdgcn_rcpf(1.f + __builtin_amdgcn_exp2f(-xp));
}
__device__ __forceinline__ float tanh_p(float xp2){           // pre-scaled by 2*log2e
  return 1.f - 2.f * __builtin_amdgcn_rcpf(1.f + __builtin_amdgcn_exp2f(xp2));
}
__device__ __forceinline__ bf16x8 ldw(const float* p, float s){
  bf16x8 r;
#pragma unroll
  for (int e=0;e<8;++e) r[e] = (short)f2bf(p[e]*s);
  return r;
}
__device__ __forceinline__ bf16x8 ldws(const float* pa, const float* pb, float s){
  bf16x8 r;
#pragma unroll
  for (int e=0;e<8;++e) r[e] = (short)f2bf((pa[e]+pb[e])*s);
  return r;
}
__device__ __forceinline__ bf16x8 ldxf(const float* p){       // 8 f32 -> bf16x8
  f32x4 v0 = *(const f32x4*)(p);
  f32x4 v1 = *(const f32x4*)(p+4);
  bf16x8 r;
  r[0]=(short)f2bf(v0[0]); r[1]=(short)f2bf(v0[1]);
  r[2]=(short)f2bf(v0[2]); r[3]=(short)f2bf(v0[3]);
  r[4]=(short)f2bf(v1[0]); r[5]=(short)f2bf(v1[1]);
  r[6]=(short)f2bf(v1[2]); r[7]=(short)f2bf(v1[3]);
  return r;
}

__global__ __launch_bounds__(NT, 4) void lstm_ae(
    const float* __restrict__ x,
    const float* __restrict__ eWih, const float* __restrict__ eWhh,
    const float* __restrict__ ebih, const float* __restrict__ ebhh,
    const float* __restrict__ dWih, const float* __restrict__ dWhh,
    const float* __restrict__ dbih, const float* __restrict__ dbhh,
    const float* __restrict__ fcW,  const float* __restrict__ fcb,
    float* __restrict__ out)
{
  __shared__ __attribute__((aligned(16))) unsigned short hbuf[2][HROW];

  const int tid  = threadIdx.x;
  const int lane = tid & 63;
  const int wv   = tid >> 6;          // owns cols 16wv..16wv+15, all 4 gates
  const int c16  = lane & 15;
  const int quad = lane >> 4;
  const int col  = wv*16 + c16;
  const int bg0  = blockIdx.x;        // one batch row per block

  for (int i = tid; i < 2*HROW; i += NT) ((unsigned short*)&hbuf[0][0])[i] = 0;

  // ---- encoder weights -> registers ----
  bf16x8 W[4][4], wx[4];
  f32x4 bias4[4];
#pragma unroll
  for (int g=0;g<4;++g){
    int n = g*128 + col;
    float s = (g==2) ? 2.f*LOG2E : LOG2E;
#pragma unroll
    for (int m=0;m<4;++m) W[g][m] = ldw(eWhh + (size_t)n*Hsz + m*32 + quad*8, s);
    wx[g] = ldw(eWih + (size_t)n*Isz + quad*8, s);
    float b = (ebih[n] + ebhh[n]) * s;
    bias4[g][0]=b; bias4[g][1]=b; bias4[g][2]=b; bias4[g][3]=b;
  }

  const f32x4 zero4 = {0.f,0.f,0.f,0.f};
  float cst = 0.f;                    // cell state (valid everywhere; row = batch for all quads)

  const unsigned short* rd0 = &hbuf[0][0] + quad*8;   // all A-rows read the same batch h
  const unsigned short* rd1 = &hbuf[1][0] + quad*8;
  unsigned short* wr0 = &hbuf[1][col];                // quad 0 writes (C row 0)
  unsigned short* wr1 = &hbuf[0][col];

  // 3-term gate merge (bias folded into X's C-operand); only quad 0 holds valid C rows
  auto act3 = [&](const f32x4* P, const f32x4* Q, const f32x4* X,
                  unsigned short* wp, bool upd){
    float pi = (P[0][0] + Q[0][0]) + X[0][0];
    float pf = (P[1][0] + Q[1][0]) + X[1][0];
    float pg = (P[2][0] + Q[2][0]) + X[2][0];
    float po = (P[3][0] + Q[3][0]) + X[3][0];
    float iv = sigm_p(pi), fv = sigm_p(pf), ov = sigm_p(po);
    float gv = tanh_p(pg);
    float cn = fv*cst + iv*gv;
    if (upd) cst = cn;
    float r  = __builtin_amdgcn_rcpf(1.f + __builtin_amdgcn_exp2f(cn*(2.f*LOG2E)));
    float hv = __builtin_fmaf(r, -2.f*ov, ov);      // ov*tanh(cn)
    if (quad == 0) *wp = (unsigned short)cvtpk(hv, hv);
  };
  auto act2 = [&](const f32x4* P, const f32x4* Q, unsigned short* wp){
    float pi = P[0][0] + Q[0][0];
    float pf = P[1][0] + Q[1][0];
    float pg = P[2][0] + Q[2][0];
    float po = P[3][0] + Q[3][0];
    float iv = sigm_p(pi), fv = sigm_p(pf), ov = sigm_p(po);
    float gv = tanh_p(pg);
    float cn = fv*cst + iv*gv;      // cst = enc_c, never updated in decoder
    float r  = __builtin_amdgcn_rcpf(1.f + __builtin_amdgcn_exp2f(cn*(2.f*LOG2E)));
    float hv = __builtin_fmaf(r, -2.f*ov, ov);
    if (quad == 0) *wp = (unsigned short)cvtpk(hv, hv);
  };

  // ---------------- encoder ----------------
  const float* xb = x + (size_t)bg0*SI + quad*8;   // lane slice of x[bg0][t]
  bf16x8 axc = ldxf(xb);
  const float* pX = xb + Isz;                      // x(t+1) prefetch pointer

  auto ebody = [&](const unsigned short* rd, unsigned short* wp, const float* pa){
    bf16x8 nx = ldxf(pa);            // issue early: vmem latency hides under MFMAs
    bf16x8 a0 = *(const bf16x8*)(rd);
    bf16x8 a1 = *(const bf16x8*)(rd+32);
    bf16x8 a2 = *(const bf16x8*)(rd+64);
    bf16x8 a3 = *(const bf16x8*)(rd+96);
    f32x4 P[4], Q[4], X[4];
#pragma unroll
    for (int g=0;g<4;++g) X[g] = __builtin_amdgcn_mfma_f32_16x16x32_bf16(axc, wx[g], bias4[g], 0,0,0);
#pragma unroll
    for (int g=0;g<4;++g) P[g] = __builtin_amdgcn_mfma_f32_16x16x32_bf16(a0, W[g][0], zero4, 0,0,0);
#pragma unroll
    for (int g=0;g<4;++g) Q[g] = __builtin_amdgcn_mfma_f32_16x16x32_bf16(a2, W[g][2], zero4, 0,0,0);
#pragma unroll
    for (int g=0;g<4;++g) P[g] = __builtin_amdgcn_mfma_f32_16x16x32_bf16(a1, W[g][1], P[g], 0,0,0);
#pragma unroll
    for (int g=0;g<4;++g) Q[g] = __builtin_amdgcn_mfma_f32_16x16x32_bf16(a3, W[g][3], Q[g], 0,0,0);
    act3(P, Q, X, wp, true);
    axc = nx;
    __syncthreads();
  };

  __syncthreads();   // hbuf zeroed

  // 512 steps = 255 pairs + 2 hoisted tails (prefetch pointer pinned in-bounds)
  for (int it=0; it<255; ++it){
    ebody(rd0, wr0, pX); pX += 32;
    ebody(rd1, wr1, pX); pX += 32;
  }
  ebody(rd0, wr0, pX);   // t=510: prefetch x(511)
  ebody(rd1, wr1, pX);   // t=511: prefetch x(511) again (value unused, in-bounds)
  // enc_h in hbuf[0]; cst = enc_c

  // ---------------- decoder ----------------
#pragma unroll
  for (int g=0;g<4;++g){
    int n = g*128 + col;
    float s = (g==2) ? 2.f*LOG2E : LOG2E;
    float b = (dbih[n] + dbhh[n]) * s;
    bias4[g][0]=b; bias4[g][1]=b; bias4[g][2]=b; bias4[g][3]=b;
  }

  // step 0: gates = enc_h @ dWhh^T + b (cell stays enc_c; enc_h in hbuf[0])
#pragma unroll
  for (int g=0;g<4;++g){
    int n = g*128 + col;
    float s = (g==2) ? 2.f*LOG2E : LOG2E;
#pragma unroll
    for (int m=0;m<4;++m) W[g][m] = ldw(dWhh + (size_t)n*Hsz + m*32 + quad*8, s);
  }
  {
    bf16x8 a0 = *(const bf16x8*)(rd0);
    bf16x8 a1 = *(const bf16x8*)(rd0+32);
    bf16x8 a2 = *(const bf16x8*)(rd0+64);
    bf16x8 a3 = *(const bf16x8*)(rd0+96);
    f32x4 P[4], Q[4];
#pragma unroll
    for (int g=0;g<4;++g) P[g] = __builtin_amdgcn_mfma_f32_16x16x32_bf16(a0, W[g][0], zero4, 0,0,0);
#pragma unroll
    for (int g=0;g<4;++g) Q[g] = __builtin_amdgcn_mfma_f32_16x16x32_bf16(a2, W[g][2], bias4[g], 0,0,0);
#pragma unroll
    for (int g=0;g<4;++g) P[g] = __builtin_amdgcn_mfma_f32_16x16x32_bf16(a1, W[g][1], P[g], 0,0,0);
#pragma unroll
    for (int g=0;g<4;++g) Q[g] = __builtin_amdgcn_mfma_f32_16x16x32_bf16(a3, W[g][3], Q[g], 0,0,0);
    act2(P, Q, wr0);
    __syncthreads();
  }

  // steps >=1: W = (dWih + dWhh); fc on waves 6,7 only (R1-proven mapping)
#pragma unroll
  for (int g=0;g<4;++g){
    int n = g*128 + col;
    float s = (g==2) ? 2.f*LOG2E : LOG2E;
#pragma unroll
    for (int m=0;m<4;++m){
      const float* pa = dWih + (size_t)n*Hsz + m*32 + quad*8;
      const float* pb = dWhh + (size_t)n*Hsz + m*32 + quad*8;
      W[g][m] = ldws(pa, pb, s);
    }
  }
  bf16x8 wf[4];
  f32x4 biasf4 = {0.f,0.f,0.f,0.f};
  const int nf = (wv >= 6) ? (wv-6)*16 + c16 : 0;
  if (wv >= 6){
#pragma unroll
    for (int m=0;m<4;++m) wf[m] = ldw(fcW + (size_t)nf*Hsz + m*32 + quad*8, 1.f);
    float bfc = fcb[nf];
    biasf4[0]=bfc; biasf4[1]=bfc; biasf4[2]=bfc; biasf4[3]=bfc;
  }
  float* fp = out + (size_t)bg0*SI + nf;   // frame slot, +32 floats/step

  auto dbody = [&](const unsigned short* rd, unsigned short* wp, float* fpp){
    bf16x8 a0 = *(const bf16x8*)(rd);
    bf16x8 a1 = *(const bf16x8*)(rd+32);
    bf16x8 a2 = *(const bf16x8*)(rd+64);
    bf16x8 a3 = *(const bf16x8*)(rd+96);
    f32x4 P[4], Q[4];
#pragma unroll
    for (int g=0;g<4;++g) P[g] = __builtin_amdgcn_mfma_f32_16x16x32_bf16(a0, W[g][0], zero4, 0,0,0);
#pragma unroll
    for (int g=0;g<4;++g) Q[g] = __builtin_amdgcn_mfma_f32_16x16x32_bf16(a2, W[g][2], bias4[g], 0,0,0);
#pragma unroll
    for (int g=0;g<4;++g) P[g] = __builtin_amdgcn_mfma_f32_16x16x32_bf16(a1, W[g][1], P[g], 0,0,0);
#pragma unroll
    for (int g=0;g<4;++g) Q[g] = __builtin_amdgcn_mfma_f32_16x16x32_bf16(a3, W[g][3], Q[g], 0,0,0);
    if (wv >= 6){
      f32x4 fa = __builtin_amdgcn_mfma_f32_16x16x32_bf16(a0, wf[0], biasf4, 0,0,0);
      f32x4 fb = __builtin_amdgcn_mfma_f32_16x16x32_bf16(a2, wf[2], zero4, 0,0,0);
      fa = __builtin_amdgcn_mfma_f32_16x16x32_bf16(a1, wf[1], fa, 0,0,0);
      fb = __builtin_amdgcn_mfma_f32_16x16x32_bf16(a3, wf[3], fb, 0,0,0);
      act2(P, Q, wp);
      if (quad == 0) *fpp = fa[0] + fb[0];
    } else {
      act2(P, Q, wp);
    }
    __syncthreads();
  };

  // t = 1..510 (255 pairs), then t = 511 (stores frames 0..510)
  for (int it=0; it<255; ++it){
    dbody(rd1, wr1, fp); fp += 32;
    dbody(rd0, wr0, fp); fp += 32;
  }
  dbody(rd1, wr1, fp); fp += 32;

  // epilogue: frame 511 from h(511) (in hbuf[0])
  if (wv >= 6){
    bf16x8 a0 = *(const bf16x8*)(rd0);
    bf16x8 a1 = *(const bf16x8*)(rd0+32);
    bf16x8 a2 = *(const bf16x8*)(rd0+64);
    bf16x8 a3 = *(const bf16x8*)(rd0+96);
    f32x4 fa = __builtin_amdgcn_mfma_f32_16x16x32_bf16(a0, wf[0], biasf4, 0,0,0);
    f32x4 fb = __builtin_amdgcn_mfma_f32_16x16x32_bf16(a2, wf[2], zero4, 0,0,0);
    fa = __builtin_amdgcn_mfma_f32_16x16x32_bf16(a1, wf[1], fa, 0,0,0);
    fb = __builtin_amdgcn_mfma_f32_16x16x32_bf16(a3, wf[3], fb, 0,0,0);
    if (quad == 0) *fp = fa[0] + fb[0];
  }
}

extern "C" void kernel_launch(void* const* d_in, const int* in_sizes, int n_in,
                              void* d_out, int out_size, void* d_ws, size_t ws_size,
                              hipStream_t stream) {
  const float* x    = (const float*)d_in[0];
  const float* eWih = (const float*)d_in[1];
  const float* eWhh = (const float*)d_in[2];
  const float* ebih = (const float*)d_in[3];
  const float* ebhh = (const float*)d_in[4];
  const float* dWih = (const float*)d_in[5];
  const float* dWhh = (const float*)d_in[6];
  const float* dbih = (const float*)d_in[7];
  const float* dbhh = (const float*)d_in[8];
  const float* fcW  = (const float*)d_in[9];
  const float* fcb  = (const float*)d_in[10];
  float* outp = (float*)d_out;
  (void)d_ws; (void)ws_size; (void)in_sizes; (void)n_in; (void)out_size;
  lstm_ae<<<dim3(Bsz/BB), dim3(NT), 0, stream>>>(
      x, eWih, eWhh, ebih, ebhh, dWih, dWhh, dbih, dbhh, fcW, fcb, outp);
}

// Round 6
// 1069.556 us; speedup vs baseline: 2.2883x; 2.2883x over previous
//
#include <hip/hip_runtime.h>

#define Bsz 512
#define Ssz 512
#define Isz 32
#define Hsz 128
#define BB  1            // one batch row per block -> grid 512 -> 2 blocks/CU possible
#define NT  512          // 8 waves
#define SI  (Ssz*Isz)    // 16384
#define HROW 144         // shorts per h row: 288 B stride
#define LOG2E 1.44269504088896340736f

typedef __attribute__((ext_vector_type(8))) short bf16x8;
typedef __attribute__((ext_vector_type(4))) float f32x4;
typedef __attribute__((ext_vector_type(2))) unsigned int u32x2;

__device__ __forceinline__ unsigned cvtpk(float lo, float hi){
  unsigned r; asm("v_cvt_pk_bf16_f32 %0, %1, %2" : "=v"(r) : "v"(lo), "v"(hi));
  return r;
}
__device__ __forceinline__ unsigned short f2bf(float f){      // RNE f32->bf16
  unsigned u = __float_as_uint(f);
  return (unsigned short)((u + 0x7FFFu + ((u >> 16) & 1u)) >> 16);
}
__device__ __forceinline__ float sigm_p(float xp){            // pre-scaled by log2e
  return __builtin_amdgcn_rcpf(1.f + __builtin_amdgcn_exp2f(-xp));
}
__device__ __forceinline__ float tanh_p(float xp2){           // pre-scaled by 2*log2e
  return 1.f - 2.f * __builtin_amdgcn_rcpf(1.f + __builtin_amdgcn_exp2f(xp2));
}
__device__ __forceinline__ bf16x8 ldw(const float* p, float s){
  bf16x8 r;
#pragma unroll
  for (int e=0;e<8;++e) r[e] = (short)f2bf(p[e]*s);
  return r;
}
__device__ __forceinline__ bf16x8 ldws(const float* pa, const float* pb, float s){
  bf16x8 r;
#pragma unroll
  for (int e=0;e<8;++e) r[e] = (short)f2bf((pa[e]+pb[e])*s);
  return r;
}

__global__ __launch_bounds__(NT, 2) void lstm_ae(
    const float* __restrict__ x,
    const float* __restrict__ eWih, const float* __restrict__ eWhh,
    const float* __restrict__ ebih, const float* __restrict__ ebhh,
    const float* __restrict__ dWih, const float* __restrict__ dWhh,
    const float* __restrict__ dbih, const float* __restrict__ dbhh,
    const float* __restrict__ fcW,  const float* __restrict__ fcb,
    float* __restrict__ out)
{
  __shared__ __attribute__((aligned(16))) unsigned short xl[SI + 32];  // 32 KB + tail pad
  __shared__ __attribute__((aligned(16))) unsigned short hbuf[2][HROW];

  const int tid  = threadIdx.x;
  const int lane = tid & 63;
  const int wv   = tid >> 6;          // owns cols 16wv..16wv+15, all 4 gates
  const int c16  = lane & 15;
  const int quad = lane >> 4;
  const int col  = wv*16 + c16;
  const int bg0  = blockIdx.x;        // one batch row per block

  // ---- stage x (one batch row) as bf16 into LDS ----
  for (int i = tid*4; i < SI; i += NT*4){
    f32x4 v = *(const f32x4*)(x + (size_t)bg0*SI + i);
    u32x2 r; r[0] = cvtpk(v[0], v[1]); r[1] = cvtpk(v[2], v[3]);
    *(u32x2*)(xl + i) = r;
  }
  for (int i = tid; i < 32; i += NT) xl[SI + i] = 0;       // pad (tail prefetch, unused)
  for (int i = tid; i < 2*HROW; i += NT) ((unsigned short*)&hbuf[0][0])[i] = 0;

  // ---- encoder weights -> registers ----
  bf16x8 W[4][4], wx[4];
  f32x4 bias4[4];
#pragma unroll
  for (int g=0;g<4;++g){
    int n = g*128 + col;
    float s = (g==2) ? 2.f*LOG2E : LOG2E;
#pragma unroll
    for (int m=0;m<4;++m) W[g][m] = ldw(eWhh + (size_t)n*Hsz + m*32 + quad*8, s);
    wx[g] = ldw(eWih + (size_t)n*Isz + quad*8, s);
    float b = (ebih[n] + ebhh[n]) * s;
    bias4[g][0]=b; bias4[g][1]=b; bias4[g][2]=b; bias4[g][3]=b;
  }

  const f32x4 zero4 = {0.f,0.f,0.f,0.f};
  float cst = 0.f;                    // cell state (same for all quads; row = the batch row)

  const unsigned short* rd0 = &hbuf[0][0] + quad*8;   // all A-rows read the same batch h
  const unsigned short* rd1 = &hbuf[1][0] + quad*8;
  unsigned short* wr0 = &hbuf[1][col];                // quad 0 writes (C row 0)
  unsigned short* wr1 = &hbuf[0][col];

  // 3-term gate merge (bias folded into X's C-operand)
  auto act3 = [&](const f32x4* P, const f32x4* Q, const f32x4* X,
                  unsigned short* wp, bool upd){
    float pi = (P[0][0] + Q[0][0]) + X[0][0];
    float pf = (P[1][0] + Q[1][0]) + X[1][0];
    float pg = (P[2][0] + Q[2][0]) + X[2][0];
    float po = (P[3][0] + Q[3][0]) + X[3][0];
    float iv = sigm_p(pi), fv = sigm_p(pf), ov = sigm_p(po);
    float gv = tanh_p(pg);
    float cn = fv*cst + iv*gv;
    if (upd) cst = cn;
    float r  = __builtin_amdgcn_rcpf(1.f + __builtin_amdgcn_exp2f(cn*(2.f*LOG2E)));
    float hv = __builtin_fmaf(r, -2.f*ov, ov);      // ov*tanh(cn)
    if (quad == 0) *wp = (unsigned short)cvtpk(hv, hv);
  };
  auto act2 = [&](const f32x4* P, const f32x4* Q, unsigned short* wp){
    float pi = P[0][0] + Q[0][0];
    float pf = P[1][0] + Q[1][0];
    float pg = P[2][0] + Q[2][0];
    float po = P[3][0] + Q[3][0];
    float iv = sigm_p(pi), fv = sigm_p(pf), ov = sigm_p(po);
    float gv = tanh_p(pg);
    float cn = fv*cst + iv*gv;      // cst = enc_c, never updated in decoder
    float r  = __builtin_amdgcn_rcpf(1.f + __builtin_amdgcn_exp2f(cn*(2.f*LOG2E)));
    float hv = __builtin_fmaf(r, -2.f*ov, ov);
    if (quad == 0) *wp = (unsigned short)cvtpk(hv, hv);
  };

  // ---------------- encoder ----------------
  const unsigned short* xq = xl + quad*8;          // lane slice of x[t]
  bf16x8 axc = *(const bf16x8*)(xq);
  const unsigned short* xp = xq + 32;              // x(t+1) prefetch pointer

  auto ebody = [&](const unsigned short* rd, unsigned short* wp, const unsigned short* pa){
    bf16x8 nx = *(const bf16x8*)(pa);
    bf16x8 a0 = *(const bf16x8*)(rd);
    bf16x8 a1 = *(const bf16x8*)(rd+32);
    bf16x8 a2 = *(const bf16x8*)(rd+64);
    bf16x8 a3 = *(const bf16x8*)(rd+96);
    f32x4 P[4], Q[4], X[4];
#pragma unroll
    for (int g=0;g<4;++g) X[g] = __builtin_amdgcn_mfma_f32_16x16x32_bf16(axc, wx[g], bias4[g], 0,0,0);
#pragma unroll
    for (int g=0;g<4;++g) P[g] = __builtin_amdgcn_mfma_f32_16x16x32_bf16(a0, W[g][0], zero4, 0,0,0);
#pragma unroll
    for (int g=0;g<4;++g) Q[g] = __builtin_amdgcn_mfma_f32_16x16x32_bf16(a2, W[g][2], zero4, 0,0,0);
#pragma unroll
    for (int g=0;g<4;++g) P[g] = __builtin_amdgcn_mfma_f32_16x16x32_bf16(a1, W[g][1], P[g], 0,0,0);
#pragma unroll
    for (int g=0;g<4;++g) Q[g] = __builtin_amdgcn_mfma_f32_16x16x32_bf16(a3, W[g][3], Q[g], 0,0,0);
    act3(P, Q, X, wp, true);
    axc = nx;
    __syncthreads();
  };

  __syncthreads();   // x staged, hbuf zeroed

  // 512 steps = 255 pairs + 2 hoisted tails (prefetch pointer pinned in-bounds)
  for (int it=0; it<255; ++it){
    ebody(rd0, wr0, xp); xp += 32;
    ebody(rd1, wr1, xp); xp += 32;
  }
  ebody(rd0, wr0, xp);   // t=510: prefetch x(511)
  ebody(rd1, wr1, xp);   // t=511: prefetch pad (value unused, in-bounds)
  // enc_h in hbuf[0]; cst = enc_c

  // ---------------- decoder ----------------
#pragma unroll
  for (int g=0;g<4;++g){
    int n = g*128 + col;
    float s = (g==2) ? 2.f*LOG2E : LOG2E;
    float b = (dbih[n] + dbhh[n]) * s;
    bias4[g][0]=b; bias4[g][1]=b; bias4[g][2]=b; bias4[g][3]=b;
  }

  // step 0: gates = enc_h @ dWhh^T + b (cell stays enc_c; enc_h in hbuf[0])
#pragma unroll
  for (int g=0;g<4;++g){
    int n = g*128 + col;
    float s = (g==2) ? 2.f*LOG2E : LOG2E;
#pragma unroll
    for (int m=0;m<4;++m) W[g][m] = ldw(dWhh + (size_t)n*Hsz + m*32 + quad*8, s);
  }
  {
    bf16x8 a0 = *(const bf16x8*)(rd0);
    bf16x8 a1 = *(const bf16x8*)(rd0+32);
    bf16x8 a2 = *(const bf16x8*)(rd0+64);
    bf16x8 a3 = *(const bf16x8*)(rd0+96);
    f32x4 P[4], Q[4];
#pragma unroll
    for (int g=0;g<4;++g) P[g] = __builtin_amdgcn_mfma_f32_16x16x32_bf16(a0, W[g][0], zero4, 0,0,0);
#pragma unroll
    for (int g=0;g<4;++g) Q[g] = __builtin_amdgcn_mfma_f32_16x16x32_bf16(a2, W[g][2], bias4[g], 0,0,0);
#pragma unroll
    for (int g=0;g<4;++g) P[g] = __builtin_amdgcn_mfma_f32_16x16x32_bf16(a1, W[g][1], P[g], 0,0,0);
#pragma unroll
    for (int g=0;g<4;++g) Q[g] = __builtin_amdgcn_mfma_f32_16x16x32_bf16(a3, W[g][3], Q[g], 0,0,0);
    act2(P, Q, wr0);
    __syncthreads();
  }

  // steps >=1: W = (dWih + dWhh); fc on waves 6,7 only
#pragma unroll
  for (int g=0;g<4;++g){
    int n = g*128 + col;
    float s = (g==2) ? 2.f*LOG2E : LOG2E;
#pragma unroll
    for (int m=0;m<4;++m){
      const float* pa = dWih + (size_t)n*Hsz + m*32 + quad*8;
      const float* pb = dWhh + (size_t)n*Hsz + m*32 + quad*8;
      W[g][m] = ldws(pa, pb, s);
    }
  }
  bf16x8 wf[4];
  f32x4 biasf4 = {0.f,0.f,0.f,0.f};
  const int nf = (wv >= 6) ? (wv-6)*16 + c16 : 0;
  if (wv >= 6){
#pragma unroll
    for (int m=0;m<4;++m) wf[m] = ldw(fcW + (size_t)nf*Hsz + m*32 + quad*8, 1.f);
    float bfc = fcb[nf];
    biasf4[0]=bfc; biasf4[1]=bfc; biasf4[2]=bfc; biasf4[3]=bfc;
  }
  float* fp = out + (size_t)bg0*SI + nf;   // frame slot, +32 floats/step

  auto dbody = [&](const unsigned short* rd, unsigned short* wp, float* fpp){
    bf16x8 a0 = *(const bf16x8*)(rd);
    bf16x8 a1 = *(const bf16x8*)(rd+32);
    bf16x8 a2 = *(const bf16x8*)(rd+64);
    bf16x8 a3 = *(const bf16x8*)(rd+96);
    f32x4 P[4], Q[4];
#pragma unroll
    for (int g=0;g<4;++g) P[g] = __builtin_amdgcn_mfma_f32_16x16x32_bf16(a0, W[g][0], zero4, 0,0,0);
#pragma unroll
    for (int g=0;g<4;++g) Q[g] = __builtin_amdgcn_mfma_f32_16x16x32_bf16(a2, W[g][2], bias4[g], 0,0,0);
#pragma unroll
    for (int g=0;g<4;++g) P[g] = __builtin_amdgcn_mfma_f32_16x16x32_bf16(a1, W[g][1], P[g], 0,0,0);
#pragma unroll
    for (int g=0;g<4;++g) Q[g] = __builtin_amdgcn_mfma_f32_16x16x32_bf16(a3, W[g][3], Q[g], 0,0,0);
    if (wv >= 6){
      f32x4 fa = __builtin_amdgcn_mfma_f32_16x16x32_bf16(a0, wf[0], biasf4, 0,0,0);
      f32x4 fb = __builtin_amdgcn_mfma_f32_16x16x32_bf16(a2, wf[2], zero4, 0,0,0);
      fa = __builtin_amdgcn_mfma_f32_16x16x32_bf16(a1, wf[1], fa, 0,0,0);
      fb = __builtin_amdgcn_mfma_f32_16x16x32_bf16(a3, wf[3], fb, 0,0,0);
      act2(P, Q, wp);
      if (quad == 0) *fpp = fa[0] + fb[0];
    } else {
      act2(P, Q, wp);
    }
    __syncthreads();
  };

  // t = 1..510 (255 pairs), then t = 511 (stores frames 0..510)
  for (int it=0; it<255; ++it){
    dbody(rd1, wr1, fp); fp += 32;
    dbody(rd0, wr0, fp); fp += 32;
  }
  dbody(rd1, wr1, fp); fp += 32;

  // epilogue: frame 511 from h(511) (in hbuf[0])
  if (wv >= 6){
    bf16x8 a0 = *(const bf16x8*)(rd0);
    bf16x8 a1 = *(const bf16x8*)(rd0+32);
    bf16x8 a2 = *(const bf16x8*)(rd0+64);
    bf16x8 a3 = *(const bf16x8*)(rd0+96);
    f32x4 fa = __builtin_amdgcn_mfma_f32_16x16x32_bf16(a0, wf[0], biasf4, 0,0,0);
    f32x4 fb = __builtin_amdgcn_mfma_f32_16x16x32_bf16(a2, wf[2], zero4, 0,0,0);
    fa = __builtin_amdgcn_mfma_f32_16x16x32_bf16(a1, wf[1], fa, 0,0,0);
    fb = __builtin_amdgcn_mfma_f32_16x16x32_bf16(a3, wf[3], fb, 0,0,0);
    if (quad == 0) *fp = fa[0] + fb[0];
  }
}

extern "C" void kernel_launch(void* const* d_in, const int* in_sizes, int n_in,
                              void* d_out, int out_size, void* d_ws, size_t ws_size,
                              hipStream_t stream) {
  const float* x    = (const float*)d_in[0];
  const float* eWih = (const float*)d_in[1];
  const float* eWhh = (const float*)d_in[2];
  const float* ebih = (const float*)d_in[3];
  const float* ebhh = (const float*)d_in[4];
  const float* dWih = (const float*)d_in[5];
  const float* dWhh = (const float*)d_in[6];
  const float* dbih = (const float*)d_in[7];
  const float* dbhh = (const float*)d_in[8];
  const float* fcW  = (const float*)d_in[9];
  const float* fcb  = (const float*)d_in[10];
  float* outp = (float*)d_out;
  (void)d_ws; (void)ws_size; (void)in_sizes; (void)n_in; (void)out_size;
  lstm_ae<<<dim3(Bsz/BB), dim3(NT), 0, stream>>>(
      x, eWih, eWhh, ebih, ebhh, dWih, dWhh, dbih, dbhh, fcW, fcb, outp);
}

// Round 7
// 598.257 us; speedup vs baseline: 4.0910x; 1.7878x over previous
//
#include <hip/hip_runtime.h>

#define Bsz 512
#define Ssz 512
#define Isz 32
#define Hsz 128
#define BB  4            // 4 batch rows per block -> grid 128
#define NT  512          // 8 waves
#define SI  (Ssz*Isz)    // 16384
#define XROW 16416       // shorts per staged-x row (pad absorbs tail overread)
#define HROW 144         // shorts per h row: 288 B stride
#define LOG2E 1.44269504088896340736f

typedef __attribute__((ext_vector_type(8))) short bf16x8;
typedef __attribute__((ext_vector_type(4))) float f32x4;
typedef __attribute__((ext_vector_type(2))) unsigned int u32x2;

__device__ __forceinline__ unsigned cvtpk(float lo, float hi){
  unsigned r; asm("v_cvt_pk_bf16_f32 %0, %1, %2" : "=v"(r) : "v"(lo), "v"(hi));
  return r;
}
__device__ __forceinline__ unsigned short f2bf(float f){      // one-time weight loads
  unsigned u = __float_as_uint(f);
  return (unsigned short)((u + 0x7FFFu + ((u >> 16) & 1u)) >> 16);
}
__device__ __forceinline__ float sigm_p(float xp){            // pre-scaled by log2e
  return __builtin_amdgcn_rcpf(1.f + __builtin_amdgcn_exp2f(-xp));
}
__device__ __forceinline__ float tanh_p(float xp2){           // pre-scaled by 2*log2e
  return 1.f - 2.f * __builtin_amdgcn_rcpf(1.f + __builtin_amdgcn_exp2f(xp2));
}
__device__ __forceinline__ bf16x8 ldw(const float* p, float s){
  bf16x8 r;
#pragma unroll
  for (int e=0;e<8;++e) r[e] = (short)f2bf(p[e]*s);
  return r;
}
__device__ __forceinline__ bf16x8 ldws(const float* pa, const float* pb, float s){
  bf16x8 r;
#pragma unroll
  for (int e=0;e<8;++e) r[e] = (short)f2bf((pa[e]+pb[e])*s);
  return r;
}

// barrier that drains LDS only (lgkmcnt), NOT vmcnt: the decoder's global
// frame stores float across it instead of stalling all 8 waves on L2 acks.
// NO sched_barrier pins (m141 lesson — R2 bundled them and regressed).
__device__ __forceinline__ void barrier_lds_only(){
  asm volatile("s_waitcnt lgkmcnt(0)\n\ts_barrier" ::: "memory");
}

__global__ __launch_bounds__(NT, 2) void lstm_ae(
    const float* __restrict__ x,
    const float* __restrict__ eWih, const float* __restrict__ eWhh,
    const float* __restrict__ ebih, const float* __restrict__ ebhh,
    const float* __restrict__ dWih, const float* __restrict__ dWhh,
    const float* __restrict__ dbih, const float* __restrict__ dbhh,
    const float* __restrict__ fcW,  const float* __restrict__ fcb,
    float* __restrict__ out)
{
  __shared__ __attribute__((aligned(16))) unsigned short xl[BB*XROW];
  __shared__ __attribute__((aligned(16))) unsigned short hbuf[2][BB][HROW];

  const int tid  = threadIdx.x;
  const int lane = tid & 63;
  const int wv   = tid >> 6;          // owns cols 16wv..16wv+15, all 4 gates
  const int c16  = lane & 15;
  const int quad = lane >> 4;
  const int hrow = c16 >> 2;          // batch row replicated into 4 A-rows
  const int col  = wv*16 + c16;
  const int bg0  = blockIdx.x * BB;

  // ---- stage x (4 batch rows) as bf16 into LDS ----
#pragma unroll 2
  for (int i = tid*4; i < BB*SI; i += NT*4){
    f32x4 v = *(const f32x4*)(x + (size_t)bg0*SI + i);
    u32x2 r; r[0] = cvtpk(v[0], v[1]); r[1] = cvtpk(v[2], v[3]);
    *(u32x2*)(xl + (i>>14)*XROW + (i & (SI-1))) = r;
  }
  for (int i = tid; i < 2*BB*HROW; i += NT) ((unsigned short*)&hbuf[0][0][0])[i] = 0;

  // ---- encoder weights -> registers ----
  bf16x8 W[4][4], wx[4];
  f32x4 bias4[4];
#pragma unroll
  for (int g=0;g<4;++g){
    int n = g*128 + col;
    float s = (g==2) ? 2.f*LOG2E : LOG2E;
#pragma unroll
    for (int m=0;m<4;++m) W[g][m] = ldw(eWhh + (size_t)n*Hsz + m*32 + quad*8, s);
    wx[g] = ldw(eWih + (size_t)n*Isz + quad*8, s);
    float b = (ebih[n] + ebhh[n]) * s;
    bias4[g][0]=b; bias4[g][1]=b; bias4[g][2]=b; bias4[g][3]=b;
  }

  const f32x4 zero4 = {0.f,0.f,0.f,0.f};
  float cst = 0.f;                    // cell state: lane (quad,c16) owns batch row=quad

  const unsigned short* rd0 = &hbuf[0][hrow][0] + quad*8;
  const unsigned short* rd1 = &hbuf[1][hrow][0] + quad*8;
  unsigned short* wr0 = &hbuf[1][quad][col];
  unsigned short* wr1 = &hbuf[0][quad][col];

  // 3-term gate merge (bias pre-folded into X MFMA C-operand)
  auto act3 = [&](const f32x4* P, const f32x4* Q, const f32x4* X,
                  unsigned short* wp, bool upd){
    float pi = (P[0][0] + Q[0][0]) + X[0][0];
    float pf = (P[1][0] + Q[1][0]) + X[1][0];
    float pg = (P[2][0] + Q[2][0]) + X[2][0];
    float po = (P[3][0] + Q[3][0]) + X[3][0];
    float iv = sigm_p(pi), fv = sigm_p(pf), ov = sigm_p(po);
    float gv = tanh_p(pg);
    float cn = fv*cst + iv*gv;
    if (upd) cst = cn;
    float r  = __builtin_amdgcn_rcpf(1.f + __builtin_amdgcn_exp2f(cn*(2.f*LOG2E)));
    float hv = __builtin_fmaf(r, -2.f*ov, ov);      // ov*tanh(cn)
    *wp = (unsigned short)cvtpk(hv, hv);
  };
  auto act2 = [&](const f32x4* P, const f32x4* Q, unsigned short* wp){
    float pi = P[0][0] + Q[0][0];
    float pf = P[1][0] + Q[1][0];
    float pg = P[2][0] + Q[2][0];
    float po = P[3][0] + Q[3][0];
    float iv = sigm_p(pi), fv = sigm_p(pf), ov = sigm_p(po);
    float gv = tanh_p(pg);
    float cn = fv*cst + iv*gv;      // cst = enc_c, never updated in decoder
    float r  = __builtin_amdgcn_rcpf(1.f + __builtin_amdgcn_exp2f(cn*(2.f*LOG2E)));
    float hv = __builtin_fmaf(r, -2.f*ov, ov);
    *wp = (unsigned short)cvtpk(hv, hv);
  };

  auto ebody = [&](const unsigned short* rd, unsigned short* wp, bf16x8 axc,
                   const unsigned short* xp)->bf16x8{
    bf16x8 axn = *(const bf16x8*)(xp);   // prefetch FIRST: completes under MFMAs+act,
                                         // not between act and the barrier's lgkm drain
    bf16x8 a0 = *(const bf16x8*)(rd);
    bf16x8 a1 = *(const bf16x8*)(rd+32);
    bf16x8 a2 = *(const bf16x8*)(rd+64);
    bf16x8 a3 = *(const bf16x8*)(rd+96);
    f32x4 P[4], Q[4], X[4];
    // X first: 4 independent MFMAs fill the ds_read latency window; bias folded in
#pragma unroll
    for (int g=0;g<4;++g) X[g] = __builtin_amdgcn_mfma_f32_16x16x32_bf16(axc, wx[g], bias4[g], 0,0,0);
#pragma unroll
    for (int g=0;g<4;++g) P[g] = __builtin_amdgcn_mfma_f32_16x16x32_bf16(a0, W[g][0], zero4, 0,0,0);
#pragma unroll
    for (int g=0;g<4;++g) Q[g] = __builtin_amdgcn_mfma_f32_16x16x32_bf16(a2, W[g][2], zero4, 0,0,0);
#pragma unroll
    for (int g=0;g<4;++g) P[g] = __builtin_amdgcn_mfma_f32_16x16x32_bf16(a1, W[g][1], P[g], 0,0,0);
#pragma unroll
    for (int g=0;g<4;++g) Q[g] = __builtin_amdgcn_mfma_f32_16x16x32_bf16(a3, W[g][3], Q[g], 0,0,0);
    act3(P, Q, X, wp, true);
    __syncthreads();
    return axn;
  };

  __syncthreads();   // x staged, hbuf zeroed (full drain, one-time)

  // ---------------- encoder (512 steps, unrolled x2) ----------------
  const unsigned short* xq = xl + hrow*XROW + quad*8;
  bf16x8 axc = *(const bf16x8*)(xq);
  const unsigned short* xp = xq + 32;
  for (int it=0; it<Ssz/2; ++it){
    axc = ebody(rd0, wr0, axc, xp); xp += 32;
    axc = ebody(rd1, wr1, axc, xp); xp += 32;
  }

  // ---------------- decoder ----------------
#pragma unroll
  for (int g=0;g<4;++g){
    int n = g*128 + col;
    float s = (g==2) ? 2.f*LOG2E : LOG2E;
    float b = (dbih[n] + dbhh[n]) * s;
    bias4[g][0]=b; bias4[g][1]=b; bias4[g][2]=b; bias4[g][3]=b;
  }

  // step 0: gates = enc_h @ dWhh^T + b (cell stays enc_c; enc_h in hbuf[0])
#pragma unroll
  for (int g=0;g<4;++g){
    int n = g*128 + col;
    float s = (g==2) ? 2.f*LOG2E : LOG2E;
#pragma unroll
    for (int m=0;m<4;++m) W[g][m] = ldw(dWhh + (size_t)n*Hsz + m*32 + quad*8, s);
  }
  {
    bf16x8 a0 = *(const bf16x8*)(rd0);
    bf16x8 a1 = *(const bf16x8*)(rd0+32);
    bf16x8 a2 = *(const bf16x8*)(rd0+64);
    bf16x8 a3 = *(const bf16x8*)(rd0+96);
    f32x4 P[4], Q[4];
#pragma unroll
    for (int g=0;g<4;++g) P[g] = __builtin_amdgcn_mfma_f32_16x16x32_bf16(a0, W[g][0], zero4, 0,0,0);
#pragma unroll
    for (int g=0;g<4;++g) Q[g] = __builtin_amdgcn_mfma_f32_16x16x32_bf16(a2, W[g][2], bias4[g], 0,0,0);
#pragma unroll
    for (int g=0;g<4;++g) P[g] = __builtin_amdgcn_mfma_f32_16x16x32_bf16(a1, W[g][1], P[g], 0,0,0);
#pragma unroll
    for (int g=0;g<4;++g) Q[g] = __builtin_amdgcn_mfma_f32_16x16x32_bf16(a3, W[g][3], Q[g], 0,0,0);
    act2(P, Q, wr0);
    __syncthreads();
  }

  // steps >=1: W = (dWih + dWhh); fc on waves 6,7; frames streamed to global
#pragma unroll
  for (int g=0;g<4;++g){
    int n = g*128 + col;
    float s = (g==2) ? 2.f*LOG2E : LOG2E;
#pragma unroll
    for (int m=0;m<4;++m){
      const float* pa = dWih + (size_t)n*Hsz + m*32 + quad*8;
      const float* pb = dWhh + (size_t)n*Hsz + m*32 + quad*8;
      W[g][m] = ldws(pa, pb, s);
    }
  }
  bf16x8 wf[4];
  f32x4 biasf4 = {0.f,0.f,0.f,0.f};
  const int nf = (wv >= 6) ? (wv-6)*16 + c16 : 0;
  if (wv >= 6){
#pragma unroll
    for (int m=0;m<4;++m) wf[m] = ldw(fcW + (size_t)nf*Hsz + m*32 + quad*8, 1.f);
    float bfc = fcb[nf];
    biasf4[0]=bfc; biasf4[1]=bfc; biasf4[2]=bfc; biasf4[3]=bfc;
  }
  float* fp = out + (size_t)bg0*SI + quad*SI*0 + nf;   // fixed below per-quad
  fp = out + (size_t)(bg0 + quad)*SI + nf;             // frame slot, +32 floats/step

  auto dbody = [&](const unsigned short* rd, unsigned short* wp, float* fpp){
    bf16x8 a0 = *(const bf16x8*)(rd);
    bf16x8 a1 = *(const bf16x8*)(rd+32);
    bf16x8 a2 = *(const bf16x8*)(rd+64);
    bf16x8 a3 = *(const bf16x8*)(rd+96);
    f32x4 P[4], Q[4];
#pragma unroll
    for (int g=0;g<4;++g) P[g] = __builtin_amdgcn_mfma_f32_16x16x32_bf16(a0, W[g][0], zero4, 0,0,0);
#pragma unroll
    for (int g=0;g<4;++g) Q[g] = __builtin_amdgcn_mfma_f32_16x16x32_bf16(a2, W[g][2], bias4[g], 0,0,0);
#pragma unroll
    for (int g=0;g<4;++g) P[g] = __builtin_amdgcn_mfma_f32_16x16x32_bf16(a1, W[g][1], P[g], 0,0,0);
#pragma unroll
    for (int g=0;g<4;++g) Q[g] = __builtin_amdgcn_mfma_f32_16x16x32_bf16(a3, W[g][3], Q[g], 0,0,0);
    if (wv >= 6){
      f32x4 fa = __builtin_amdgcn_mfma_f32_16x16x32_bf16(a0, wf[0], biasf4, 0,0,0);
      f32x4 fb = __builtin_amdgcn_mfma_f32_16x16x32_bf16(a2, wf[2], zero4, 0,0,0);
      fa = __builtin_amdgcn_mfma_f32_16x16x32_bf16(a1, wf[1], fa, 0,0,0);
      fb = __builtin_amdgcn_mfma_f32_16x16x32_bf16(a3, wf[3], fb, 0,0,0);
      act2(P, Q, wp);
      *fpp = fa[0] + fb[0];          // fire-and-forget: barrier below drains LDS only
    } else {
      act2(P, Q, wp);
    }
    barrier_lds_only();
  };

  // t = 1..510 (255 pairs), then t = 511 (stores frames 0..510)
  for (int it=0; it<255; ++it){
    dbody(rd1, wr1, fp); fp += 32;
    dbody(rd0, wr0, fp); fp += 32;
  }
  dbody(rd1, wr1, fp); fp += 32;

  // epilogue: frame 511 from h(511) (in hbuf[0])
  if (wv >= 6){
    bf16x8 a0 = *(const bf16x8*)(rd0);
    bf16x8 a1 = *(const bf16x8*)(rd0+32);
    bf16x8 a2 = *(const bf16x8*)(rd0+64);
    bf16x8 a3 = *(const bf16x8*)(rd0+96);
    f32x4 fa = __builtin_amdgcn_mfma_f32_16x16x32_bf16(a0, wf[0], biasf4, 0,0,0);
    f32x4 fb = __builtin_amdgcn_mfma_f32_16x16x32_bf16(a2, wf[2], zero4, 0,0,0);
    fa = __builtin_amdgcn_mfma_f32_16x16x32_bf16(a1, wf[1], fa, 0,0,0);
    fb = __builtin_amdgcn_mfma_f32_16x16x32_bf16(a3, wf[3], fb, 0,0,0);
    *fp = fa[0] + fb[0];
  }
}

extern "C" void kernel_launch(void* const* d_in, const int* in_sizes, int n_in,
                              void* d_out, int out_size, void* d_ws, size_t ws_size,
                              hipStream_t stream) {
  const float* x    = (const float*)d_in[0];
  const float* eWih = (const float*)d_in[1];
  const float* eWhh = (const float*)d_in[2];
  const float* ebih = (const float*)d_in[3];
  const float* ebhh = (const float*)d_in[4];
  const float* dWih = (const float*)d_in[5];
  const float* dWhh = (const float*)d_in[6];
  const float* dbih = (const float*)d_in[7];
  const float* dbhh = (const float*)d_in[8];
  const float* fcW  = (const float*)d_in[9];
  const float* fcb  = (const float*)d_in[10];
  float* outp = (float*)d_out;
  (void)d_ws; (void)ws_size; (void)in_sizes; (void)n_in; (void)out_size;
  lstm_ae<<<dim3(Bsz/BB), dim3(NT), 0, stream>>>(
      x, eWih, eWhh, ebih, ebhh, dWih, dWhh, dbih, dbhh, fcW, fcb, outp);
}